// Round 10
// baseline (428.441 us; speedup 1.0000x reference)
//
#include <hip/hip_runtime.h>
#include <math.h>

#define BATCH 32
#define CI 8
#define CO 8
#define KCAP 4
#define DIN 16
#define DOUT 16
#define SS 32
#define HW (SS*SS)          // 1024
#define EPSF 1e-5f

// ---- workspace layout (float element offsets) ----
#define N_PLANE (BATCH*CO*DOUT*HW)         // 4,194,304 (16.8 MB)
#define OFF_PMAX  0
#define OFF_PMEAN (1*N_PLANE)
#define OFF_ACCM  (2*N_PLANE)
#define OFF_WSUM  (3*N_PLANE)
#define OFF_G     (4*N_PLANE)
#define OFF_CN    (5*N_PLANE)
#define OFF_STATS (6*N_PLANE)
#define ST_BNSUM 0
#define ST_BNSQ  8
#define ST_LNSUM 16
#define ST_LNSQ  272
#define STATS_FLOATS 528
#define OFF_WFRAG (OFF_STATS + STATS_FLOATS)    // ushort[655360] = 1.31 MB
#define OFF_BIASP (OFF_WFRAG + 327680)          // float[4096]

typedef __attribute__((ext_vector_type(8))) short bf16x8;
typedef __attribute__((ext_vector_type(16))) float f32x16;

__device__ __forceinline__ ushort f2bf(float f) {
    unsigned u = __float_as_uint(f);
    unsigned r = (u + 0x7FFFu + ((u >> 16) & 1u)) >> 16;
    return (ushort)r;
}

__device__ __forceinline__ void wave_reduce_atomic2(float a, float b, float* da, float* db) {
    #pragma unroll
    for (int off = 32; off > 0; off >>= 1) {
        a += __shfl_down(a, off);
        b += __shfl_down(b, off);
    }
    if ((threadIdx.x & 63) == 0) {
        atomicAdd(da, a);
        atomicAdd(db, b);
    }
}

// ===== Kernel 0: combined-weight fragments + permuted bias table ============
// idx < 81920: wfrag as r8 (proven). idx 81920..86015: biasperm[o][d][lg][r] =
// combined bias for m=(r&3)+8*(r>>2)+4*lg (f32, matches MFMA C-layout).
__global__ __launch_bounds__(256) void wfrag_kernel(
        const float* __restrict__ Wt, const float* __restrict__ bt,
        const float* __restrict__ Wv, const float* __restrict__ bv,
        ushort* __restrict__ wfrag, float* __restrict__ biasperm)
{
    const int idx = blockIdx.x * 256 + threadIdx.x;   // 0..86015
    if (idx < 81920) {
        const int lane = idx & 63;
        const int kk = (idx >> 6) % 10;
        const int d = (idx / 640) & 15;
        const int o = idx / 10240;
        const int m = lane & 31;
        ushort outv[8];
        #pragma unroll
        for (int e = 0; e < 8; ++e) {
            const int k = kk * 16 + (lane >> 5) * 8 + e;
            float w = 0.f;
            if (k < 144) {
                const int tap = k >> 4;
                const int din = k & 15;
                #pragma unroll
                for (int ci = 0; ci < 8; ++ci)
                    w += Wv[(o * 32 + m) * 8 + ci] *
                         Wt[((size_t)((ci * 8 + o) * 16 + d) * 16 + din) * 9 + tap];
            }
            outv[e] = f2bf(w);
        }
        uint4 st;
        st.x = (unsigned)outv[0] | ((unsigned)outv[1] << 16);
        st.y = (unsigned)outv[2] | ((unsigned)outv[3] << 16);
        st.z = (unsigned)outv[4] | ((unsigned)outv[5] << 16);
        st.w = (unsigned)outv[6] | ((unsigned)outv[7] << 16);
        *reinterpret_cast<uint4*>(wfrag + (size_t)idx * 8) = st;
    } else {
        const int i2 = idx - 81920;              // 0..4095
        const int r = i2 & 15, lgb = (i2 >> 4) & 1, d = (i2 >> 5) & 15, o = i2 >> 9;
        const int m = (r & 3) + 8 * (r >> 2) + 4 * lgb;
        float w = bv[o * 32 + m];
        #pragma unroll
        for (int ci = 0; ci < 8; ++ci)
            w += Wv[(o * 32 + m) * 8 + ci] * bt[(ci * 8 + o) * 16 + d];
        biasperm[i2] = w;
    }
}

// ===== Kernel 1: MFMA conv+einsum+pool+routing stats (512 thr, bias-init) ===
// grid (16, 32): blockIdx.x = o*2+dh, blockIdx.y = b. 8 waves; wave owns
// u = wv*4+nt rows. LDS bf16 [34][34][24], ds_write_b128 staging. K=144 (9 kk);
// bias via f32 C-init from biasperm. Epilogue: s1-reuse + fmax trees.
__global__ __launch_bounds__(512, 4) void convmfma_kernel(
        const float* __restrict__ caps, const ushort* __restrict__ wfrag,
        const float* __restrict__ biasperm,
        float* __restrict__ pmax, float* __restrict__ pmean,
        float* __restrict__ accm_g, float* __restrict__ wsum_g)
{
    __shared__ __align__(16) ushort xs[34 * 34 * 24];   // 55,488 B
    const int tid = threadIdx.x;
    const int o = blockIdx.x >> 1;
    const int dh = blockIdx.x & 1;
    const int b = blockIdx.y;

    for (int i = tid; i < 3468; i += 512)
        reinterpret_cast<uint4*>(xs)[i] = make_uint4(0u, 0u, 0u, 0u);
    __syncthreads();
    {
        const int t = tid & 255, dgrp = tid >> 8;
        const int u = t >> 3, v0 = (t & 7) * 4;
        const float* capb = caps + (size_t)b * DIN * HW + (size_t)dgrp * 8 * HW + u * SS + v0;
        float4 L0 = *reinterpret_cast<const float4*>(capb + 0 * HW);
        float4 L1 = *reinterpret_cast<const float4*>(capb + 1 * HW);
        float4 L2 = *reinterpret_cast<const float4*>(capb + 2 * HW);
        float4 L3 = *reinterpret_cast<const float4*>(capb + 3 * HW);
        float4 L4 = *reinterpret_cast<const float4*>(capb + 4 * HW);
        float4 L5 = *reinterpret_cast<const float4*>(capb + 5 * HW);
        float4 L6 = *reinterpret_cast<const float4*>(capb + 6 * HW);
        float4 L7 = *reinterpret_cast<const float4*>(capb + 7 * HW);
        #define STPX(i, COMP) do { \
            uint4 w_; \
            w_.x = (unsigned)f2bf(L0.COMP) | ((unsigned)f2bf(L1.COMP) << 16); \
            w_.y = (unsigned)f2bf(L2.COMP) | ((unsigned)f2bf(L3.COMP) << 16); \
            w_.z = (unsigned)f2bf(L4.COMP) | ((unsigned)f2bf(L5.COMP) << 16); \
            w_.w = (unsigned)f2bf(L6.COMP) | ((unsigned)f2bf(L7.COMP) << 16); \
            *reinterpret_cast<uint4*>(&xs[((u + 1) * 34 + (v0 + (i) + 1)) * 24 + dgrp * 8]) = w_; \
        } while (0)
        STPX(0, x); STPX(1, y); STPX(2, z); STPX(3, w);
        #undef STPX
    }
    __syncthreads();

    const int l = tid & 63;
    const int wv = tid >> 6;          // 0..7
    const int lg = l >> 5;
    const int v = l & 31;
    const bf16x8* wf = reinterpret_cast<const bf16x8*>(wfrag);
    constexpr int OFFS[9] = {0, 48, 96, 1632, 1680, 1728, 3264, 3312, 3360};

    #define EPILOG(C, DD) do { \
        const size_t idx_ = ((size_t)(b * 8 + o) * 16 + (DD)) * 1024 + px; \
        float s10 = (C[0] + C[4]) + (C[8] + C[12]); \
        float s11 = (C[1] + C[5]) + (C[9] + C[13]); \
        float s12 = (C[2] + C[6]) + (C[10] + C[14]); \
        float s13 = (C[3] + C[7]) + (C[11] + C[15]); \
        float vsum = (s10 + s11) + (s12 + s13); \
        float vmax = fmaxf( \
            fmaxf(fmaxf(fmaxf(C[0], C[1]), fmaxf(C[2], C[3])), \
                  fmaxf(fmaxf(C[4], C[5]), fmaxf(C[6], C[7]))), \
            fmaxf(fmaxf(fmaxf(C[8], C[9]), fmaxf(C[10], C[11])), \
                  fmaxf(fmaxf(C[12], C[13]), fmaxf(C[14], C[15])))); \
        float s20 = fmaf(C[0], C[0], fmaf(C[4], C[4], fmaf(C[8], C[8], C[12] * C[12]))); \
        float s21 = fmaf(C[1], C[1], fmaf(C[5], C[5], fmaf(C[9], C[9], C[13] * C[13]))); \
        float s22 = fmaf(C[2], C[2], fmaf(C[6], C[6], fmaf(C[10], C[10], C[14] * C[14]))); \
        float s23 = fmaf(C[3], C[3], fmaf(C[7], C[7], fmaf(C[11], C[11], C[15] * C[15]))); \
        float wsp = 0.f, amp = 0.f; \
        { float mean = 0.25f * s10; float var = fmaxf(fmaf(-mean, mean, 0.25f * s20), 1e-30f); \
          float rq = rsqrtf(var); wsp += rq; amp = fmaf(rq, mean, amp); } \
        { float mean = 0.25f * s11; float var = fmaxf(fmaf(-mean, mean, 0.25f * s21), 1e-30f); \
          float rq = rsqrtf(var); wsp += rq; amp = fmaf(rq, mean, amp); } \
        { float mean = 0.25f * s12; float var = fmaxf(fmaf(-mean, mean, 0.25f * s22), 1e-30f); \
          float rq = rsqrtf(var); wsp += rq; amp = fmaf(rq, mean, amp); } \
        { float mean = 0.25f * s13; float var = fmaxf(fmaf(-mean, mean, 0.25f * s23), 1e-30f); \
          float rq = rsqrtf(var); wsp += rq; amp = fmaf(rq, mean, amp); } \
        vmax = fmaxf(vmax, __shfl_xor(vmax, 32)); \
        vsum += __shfl_xor(vsum, 32); \
        wsp += __shfl_xor(wsp, 32); \
        amp += __shfl_xor(amp, 32); \
        if (l < 32) { pmax[idx_] = vmax; accm_g[idx_] = amp; } \
        else { pmean[idx_] = vsum * (1.f / 32.f); wsum_g[idx_] = wsp; } \
    } while (0)

    for (int dp = 0; dp < 4; ++dp) {
        const int d0 = dh * 8 + dp * 2, d1 = d0 + 1;
        bf16x8 af0[9], af1[9];
        #pragma unroll
        for (int kk = 0; kk < 9; ++kk) {
            af0[kk] = wf[(size_t)((o * 16 + d0) * 10 + kk) * 64 + l];
            af1[kk] = wf[(size_t)((o * 16 + d1) * 10 + kk) * 64 + l];
        }
        const float* bp0 = biasperm + ((o * 16 + d0) * 2 + lg) * 16;
        const float* bp1 = biasperm + ((o * 16 + d1) * 2 + lg) * 16;
        float4 q00 = *reinterpret_cast<const float4*>(bp0);
        float4 q01 = *reinterpret_cast<const float4*>(bp0 + 4);
        float4 q02 = *reinterpret_cast<const float4*>(bp0 + 8);
        float4 q03 = *reinterpret_cast<const float4*>(bp0 + 12);
        float4 q10 = *reinterpret_cast<const float4*>(bp1);
        float4 q11 = *reinterpret_cast<const float4*>(bp1 + 4);
        float4 q12 = *reinterpret_cast<const float4*>(bp1 + 8);
        float4 q13 = *reinterpret_cast<const float4*>(bp1 + 12);
        f32x16 ci0, ci1;
        ci0[0]=q00.x; ci0[1]=q00.y; ci0[2]=q00.z; ci0[3]=q00.w;
        ci0[4]=q01.x; ci0[5]=q01.y; ci0[6]=q01.z; ci0[7]=q01.w;
        ci0[8]=q02.x; ci0[9]=q02.y; ci0[10]=q02.z; ci0[11]=q02.w;
        ci0[12]=q03.x; ci0[13]=q03.y; ci0[14]=q03.z; ci0[15]=q03.w;
        ci1[0]=q10.x; ci1[1]=q10.y; ci1[2]=q10.z; ci1[3]=q10.w;
        ci1[4]=q11.x; ci1[5]=q11.y; ci1[6]=q11.z; ci1[7]=q11.w;
        ci1[8]=q12.x; ci1[9]=q12.y; ci1[10]=q12.z; ci1[11]=q12.w;
        ci1[12]=q13.x; ci1[13]=q13.y; ci1[14]=q13.z; ci1[15]=q13.w;

        for (int nt = 0; nt < 4; ++nt) {
            const int u = wv * 4 + nt;
            const int baddr = (u * 34 + v) * 48 + lg * 16;
            f32x16 c0 = ci0, c1 = ci1;
            #pragma unroll
            for (int kk = 0; kk < 9; ++kk) {
                bf16x8 bb = *reinterpret_cast<const bf16x8*>(
                    reinterpret_cast<const char*>(xs) + baddr + OFFS[kk]);
                c0 = __builtin_amdgcn_mfma_f32_32x32x16_bf16(af0[kk], bb, c0, 0, 0, 0);
                c1 = __builtin_amdgcn_mfma_f32_32x32x16_bf16(af1[kk], bb, c1, 0, 0, 0);
            }
            const int px = u * 32 + v;
            EPILOG(c0, d0);
            EPILOG(c1, d1);
        }
    }
    #undef EPILOG
}

// ===== Kernel 2: d-marching 3x3x3 stencil + BN partials (d-split x2) ========
// grid 512: blk = (b*8+o)*2 + kslab. Block owns outputs d0..d0+7 (d0=kslab*8),
// marches planes d0-1..d0+8. LDS ring 2 x {pmax,pmean} [34][40]. 2 blocks/CU.
__global__ __launch_bounds__(256) void stencil_kernel(
        const float* __restrict__ pmax, const float* __restrict__ pmean,
        const float* __restrict__ Wsp, float* __restrict__ g, float* __restrict__ stats)
{
    __shared__ float sm[2][2][34 * 40];   // 21,760 B
    __shared__ float red[8];
    const int tid = threadIdx.x;
    const int kslab = blockIdx.x & 1;
    const int o = (blockIdx.x >> 1) & 7;
    const int b = blockIdx.x >> 4;
    const int u = tid >> 3;
    const int v4 = (tid & 7) * 4;
    const size_t base = ((size_t)(b * CO + o) * DOUT) * HW;
    const int prow = u * SS + v4;
    const int d0 = kslab * 8;

    for (int i = tid; i < 2 * 2 * 34 * 40; i += 256) (&sm[0][0][0])[i] = 0.f;
    float4 ix, in_;
    const bool first_valid = (d0 - 1 >= 0);
    if (first_valid) {
        ix = *reinterpret_cast<const float4*>(pmax + base + (size_t)(d0 - 1) * HW + prow);
        in_ = *reinterpret_cast<const float4*>(pmean + base + (size_t)(d0 - 1) * HW + prow);
    }
    __syncthreads();
    if (first_valid) {
        *reinterpret_cast<float4*>(&sm[0][0][(u + 1) * 40 + v4 + 4]) = ix;
        *reinterpret_cast<float4*>(&sm[0][1][(u + 1) * 40 + v4 + 4]) = in_;
    }
    __syncthreads();

    float4 A0 = make_float4(0.f, 0.f, 0.f, 0.f);
    float4 A1 = make_float4(0.f, 0.f, 0.f, 0.f);
    float bnsum = 0.f, bnsq = 0.f;

    for (int i = 0; i < 10; ++i) {
        const int p = d0 - 1 + i;
        const int slot = i & 1;
        const bool vnext = (i < 9) && (d0 + i <= 15);
        float4 nx, nn;
        if (vnext) {
            nx = *reinterpret_cast<const float4*>(pmax + base + (size_t)(d0 + i) * HW + prow);
            nn = *reinterpret_cast<const float4*>(pmean + base + (size_t)(d0 + i) * HW + prow);
        }
        float4 A2 = make_float4(0.f, 0.f, 0.f, 0.f);
        if (p >= 0 && p <= 15) {
            #pragma unroll
            for (int a = 0; a < 2; ++a) {
                const float* sp = sm[slot][a];
                #pragma unroll
                for (int du = 0; du < 3; ++du) {
                    const int rb = (u + du) * 40;
                    const float w0 = sp[rb + v4 + 3];
                    const float4 m4 = *reinterpret_cast<const float4*>(&sp[rb + v4 + 4]);
                    const float w5 = sp[rb + v4 + 8];
                    const float w1 = m4.x, w2 = m4.y, w3 = m4.z, w4 = m4.w;
                    const int wb = a * 27 + du * 3;
                    {
                        const float c0 = Wsp[wb + 18], c1 = Wsp[wb + 19], c2 = Wsp[wb + 20];
                        A0.x += c0 * w0 + c1 * w1 + c2 * w2;
                        A0.y += c0 * w1 + c1 * w2 + c2 * w3;
                        A0.z += c0 * w2 + c1 * w3 + c2 * w4;
                        A0.w += c0 * w3 + c1 * w4 + c2 * w5;
                    }
                    {
                        const float c0 = Wsp[wb + 9], c1 = Wsp[wb + 10], c2 = Wsp[wb + 11];
                        A1.x += c0 * w0 + c1 * w1 + c2 * w2;
                        A1.y += c0 * w1 + c1 * w2 + c2 * w3;
                        A1.z += c0 * w2 + c1 * w3 + c2 * w4;
                        A1.w += c0 * w3 + c1 * w4 + c2 * w5;
                    }
                    {
                        const float c0 = Wsp[wb + 0], c1 = Wsp[wb + 1], c2 = Wsp[wb + 2];
                        A2.x += c0 * w0 + c1 * w1 + c2 * w2;
                        A2.y += c0 * w1 + c1 * w2 + c2 * w3;
                        A2.z += c0 * w2 + c1 * w3 + c2 * w4;
                        A2.w += c0 * w3 + c1 * w4 + c2 * w5;
                    }
                }
            }
        }
        if (p - 1 >= d0 && p - 1 < d0 + 8) {
            *reinterpret_cast<float4*>(&g[base + (size_t)(p - 1) * HW + prow]) = A0;
            bnsum += A0.x + A0.y + A0.z + A0.w;
            bnsq += A0.x * A0.x + A0.y * A0.y + A0.z * A0.z + A0.w * A0.w;
        }
        A0 = A1; A1 = A2;
        if (vnext) {
            *reinterpret_cast<float4*>(&sm[slot ^ 1][0][(u + 1) * 40 + v4 + 4]) = nx;
            *reinterpret_cast<float4*>(&sm[slot ^ 1][1][(u + 1) * 40 + v4 + 4]) = nn;
        }
        __syncthreads();
    }

    #pragma unroll
    for (int off = 32; off > 0; off >>= 1) {
        bnsum += __shfl_down(bnsum, off);
        bnsq += __shfl_down(bnsq, off);
    }
    if ((tid & 63) == 0) { red[tid >> 6] = bnsum; red[4 + (tid >> 6)] = bnsq; }
    __syncthreads();
    if (tid == 0) {
        atomicAdd(&stats[ST_BNSUM + o], red[0] + red[1] + red[2] + red[3]);
        atomicAdd(&stats[ST_BNSQ + o], red[4] + red[5] + red[6] + red[7]);
    }
}

// ===== Kernel 3: BN -> sigmoid gate -> caps_next + LN partials (proven) =====
__global__ __launch_bounds__(256) void finalize_kernel(
        const float* __restrict__ g, const float* __restrict__ accm_g,
        const float* __restrict__ wsum_g,
        const float* __restrict__ bn_gamma, const float* __restrict__ bn_beta,
        float* __restrict__ cn, float* __restrict__ stats)
{
    const int d = blockIdx.x & 15;
    const int o = (blockIdx.x >> 4) & 7;
    const int b = blockIdx.x >> 7;
    const int px0 = threadIdx.x * 4;

    const float nbn = 1.f / (float)(BATCH * DOUT * HW);
    const float mu = stats[ST_BNSUM + o] * nbn;
    const float var = fmaxf(stats[ST_BNSQ + o] * nbn - mu * mu, 0.f);
    const float rstd = rsqrtf(var + EPSF);
    const float gam = bn_gamma[0], bet = bn_beta[0];

    const size_t gbase = (((size_t)b * CO + o) * DOUT + d) * HW + px0;
    float4 g4 = *reinterpret_cast<const float4*>(&g[gbase]);
    float4 a4 = *reinterpret_cast<const float4*>(&accm_g[gbase]);
    float4 w4 = *reinterpret_cast<const float4*>(&wsum_g[gbase]);
    float4 cnv;
    cnv.x = (1.f + 1.f / (1.f + expf(-((g4.x - mu) * rstd * gam + bet)))) * a4.x / w4.x;
    cnv.y = (1.f + 1.f / (1.f + expf(-((g4.y - mu) * rstd * gam + bet)))) * a4.y / w4.y;
    cnv.z = (1.f + 1.f / (1.f + expf(-((g4.z - mu) * rstd * gam + bet)))) * a4.z / w4.z;
    cnv.w = (1.f + 1.f / (1.f + expf(-((g4.w - mu) * rstd * gam + bet)))) * a4.w / w4.w;
    *reinterpret_cast<float4*>(&cn[gbase]) = cnv;

    float s = cnv.x + cnv.y + cnv.z + cnv.w;
    float sq = cnv.x * cnv.x + cnv.y * cnv.y + cnv.z * cnv.z + cnv.w * cnv.w;
    wave_reduce_atomic2(s, sq, &stats[ST_LNSUM + b * CO + o], &stats[ST_LNSQ + b * CO + o]);
}

// ===== Kernel 4: LayerNorm + transpose-out (proven) =========================
__global__ __launch_bounds__(256) void ln_kernel(
        const float* __restrict__ cn, const float* __restrict__ stats,
        const float* __restrict__ lng, const float* __restrict__ lnb,
        float* __restrict__ out)
{
    const int bo = blockIdx.x;
    const int b = bo >> 3, o = bo & 7;
    const float nln = 1.f / 16384.f;
    const float mu = stats[ST_LNSUM + bo] * nln;
    const float var = fmaxf(stats[ST_LNSQ + bo] * nln - mu * mu, 0.f);
    const float rstd = rsqrtf(var + EPSF);
    const float* src = cn + (size_t)bo * 16384;
    float* dst = out + ((size_t)o * BATCH + b) * 16384;
    #pragma unroll
    for (int i = 0; i < 16; i++) {
        const int e = i * 1024 + threadIdx.x * 4;
        float4 x = *reinterpret_cast<const float4*>(src + e);
        float4 gm = *reinterpret_cast<const float4*>(lng + e);
        float4 bb = *reinterpret_cast<const float4*>(lnb + e);
        float4 y;
        y.x = (x.x - mu) * rstd * gm.x + bb.x;
        y.y = (x.y - mu) * rstd * gm.y + bb.y;
        y.z = (x.z - mu) * rstd * gm.z + bb.z;
        y.w = (x.w - mu) * rstd * gm.w + bb.w;
        *reinterpret_cast<float4*>(dst + e) = y;
    }
}

extern "C" void kernel_launch(void* const* d_in, const int* in_sizes, int n_in,
                              void* d_out, int out_size, void* d_ws, size_t ws_size,
                              hipStream_t stream) {
    const float* caps = (const float*)d_in[0];
    const float* Wt   = (const float*)d_in[1];
    const float* bt   = (const float*)d_in[2];
    const float* Wv   = (const float*)d_in[3];
    const float* bv   = (const float*)d_in[4];
    const float* Wsp  = (const float*)d_in[5];
    const float* bng  = (const float*)d_in[6];
    const float* bnb  = (const float*)d_in[7];
    const float* lng  = (const float*)d_in[8];
    const float* lnb  = (const float*)d_in[9];
    float* ws = (float*)d_ws;
    float* pmax  = ws + OFF_PMAX;
    float* pmean = ws + OFF_PMEAN;
    float* accm  = ws + OFF_ACCM;
    float* wsum  = ws + OFF_WSUM;
    float* g     = ws + OFF_G;
    float* cn    = ws + OFF_CN;
    float* stats = ws + OFF_STATS;
    ushort* wfrag = (ushort*)(ws + OFF_WFRAG);
    float* biasperm = ws + OFF_BIASP;
    float* out = (float*)d_out;

    hipMemsetAsync(stats, 0, STATS_FLOATS * sizeof(float), stream);
    wfrag_kernel<<<336, 256, 0, stream>>>(Wt, bt, Wv, bv, wfrag, biasperm);
    convmfma_kernel<<<dim3(16, 32), 512, 0, stream>>>(caps, wfrag, biasperm,
                                                      pmax, pmean, accm, wsum);
    stencil_kernel<<<512, 256, 0, stream>>>(pmax, pmean, Wsp, g, stats);
    finalize_kernel<<<4096, 256, 0, stream>>>(g, accm, wsum, bng, bnb, cn, stats);
    ln_kernel<<<256, 256, 0, stream>>>(cn, stats, lng, lnb, out);
}

// Round 11
// 206.942 us; speedup vs baseline: 2.0703x; 2.0703x over previous
//
#include <hip/hip_runtime.h>
#include <math.h>

#define BATCH 32
#define CI 8
#define CO 8
#define KCAP 4
#define DIN 16
#define DOUT 16
#define SS 32
#define HW (SS*SS)          // 1024
#define EPSF 1e-5f

// ---- workspace layout (float element offsets) ----
#define N_PLANE (BATCH*CO*DOUT*HW)         // 4,194,304 (16.8 MB)
#define OFF_PMAX  0
#define OFF_PMEAN (1*N_PLANE)
#define OFF_ACCM  (2*N_PLANE)
#define OFF_WSUM  (3*N_PLANE)
#define OFF_G     (4*N_PLANE)
#define OFF_CN    (5*N_PLANE)
#define OFF_STATS (6*N_PLANE)
#define ST_BNSUM 0
#define ST_BNSQ  8
#define ST_LNSUM 16
#define ST_LNSQ  272
#define STATS_FLOATS 528
#define OFF_WFRAG (OFF_STATS + STATS_FLOATS)    // ushort[655360] = 1.31 MB
#define OFF_BIASP (OFF_WFRAG + 327680)          // float[4096]

typedef __attribute__((ext_vector_type(8))) short bf16x8;
typedef __attribute__((ext_vector_type(16))) float f32x16;

__device__ __forceinline__ ushort f2bf(float f) {
    unsigned u = __float_as_uint(f);
    unsigned r = (u + 0x7FFFu + ((u >> 16) & 1u)) >> 16;
    return (ushort)r;
}

__device__ __forceinline__ void wave_reduce_atomic2(float a, float b, float* da, float* db) {
    #pragma unroll
    for (int off = 32; off > 0; off >>= 1) {
        a += __shfl_down(a, off);
        b += __shfl_down(b, off);
    }
    if ((threadIdx.x & 63) == 0) {
        atomicAdd(da, a);
        atomicAdd(db, b);
    }
}

// ===== Kernel 0: combined-weight fragments + permuted bias table (proven) ===
__global__ __launch_bounds__(256) void wfrag_kernel(
        const float* __restrict__ Wt, const float* __restrict__ bt,
        const float* __restrict__ Wv, const float* __restrict__ bv,
        ushort* __restrict__ wfrag, float* __restrict__ biasperm)
{
    const int idx = blockIdx.x * 256 + threadIdx.x;   // 0..86015
    if (idx < 81920) {
        const int lane = idx & 63;
        const int kk = (idx >> 6) % 10;
        const int d = (idx / 640) & 15;
        const int o = idx / 10240;
        const int m = lane & 31;
        ushort outv[8];
        #pragma unroll
        for (int e = 0; e < 8; ++e) {
            const int k = kk * 16 + (lane >> 5) * 8 + e;
            float w = 0.f;
            if (k < 144) {
                const int tap = k >> 4;
                const int din = k & 15;
                #pragma unroll
                for (int ci = 0; ci < 8; ++ci)
                    w += Wv[(o * 32 + m) * 8 + ci] *
                         Wt[((size_t)((ci * 8 + o) * 16 + d) * 16 + din) * 9 + tap];
            }
            outv[e] = f2bf(w);
        }
        uint4 st;
        st.x = (unsigned)outv[0] | ((unsigned)outv[1] << 16);
        st.y = (unsigned)outv[2] | ((unsigned)outv[3] << 16);
        st.z = (unsigned)outv[4] | ((unsigned)outv[5] << 16);
        st.w = (unsigned)outv[6] | ((unsigned)outv[7] << 16);
        *reinterpret_cast<uint4*>(wfrag + (size_t)idx * 8) = st;
    } else {
        const int i2 = idx - 81920;              // 0..4095
        const int r = i2 & 15, lgb = (i2 >> 4) & 1, d = (i2 >> 5) & 15, o = i2 >> 9;
        const int m = (r & 3) + 8 * (r >> 2) + 4 * lgb;
        float w = bv[o * 32 + m];
        #pragma unroll
        for (int ci = 0; ci < 8; ++ci)
            w += Wv[(o * 32 + m) * 8 + ci] * bt[(ci * 8 + o) * 16 + d];
        biasperm[i2] = w;
    }
}

// ===== Kernel 1: MFMA conv+einsum+pool+routing stats ========================
// r9-proven 256-thread structure + {bias C-init (9 taps), ds_write_b128
// staging, lean epilogue}. grid (16, 32): blockIdx.x = o*2+dh, blockIdx.y = b.
// NO second launch_bounds arg (r10 lesson: it caps VGPR at 64 -> spill).
__global__ __launch_bounds__(256) void convmfma_kernel(
        const float* __restrict__ caps, const ushort* __restrict__ wfrag,
        const float* __restrict__ biasperm,
        float* __restrict__ pmax, float* __restrict__ pmean,
        float* __restrict__ accm_g, float* __restrict__ wsum_g)
{
    __shared__ __align__(16) ushort xs[34 * 34 * 24];   // 55,488 B
    const int tid = threadIdx.x;
    const int o = blockIdx.x >> 1;
    const int dh = blockIdx.x & 1;
    const int b = blockIdx.y;

    for (int i = tid; i < 3468; i += 256)
        reinterpret_cast<uint4*>(xs)[i] = make_uint4(0u, 0u, 0u, 0u);
    __syncthreads();
    {
        const int u = tid >> 3, v0 = (tid & 7) * 4;
        #pragma unroll
        for (int dgrp = 0; dgrp < 2; ++dgrp) {
            const float* capb = caps + (size_t)b * DIN * HW + (size_t)dgrp * 8 * HW
                                + u * SS + v0;
            float4 L0 = *reinterpret_cast<const float4*>(capb + 0 * HW);
            float4 L1 = *reinterpret_cast<const float4*>(capb + 1 * HW);
            float4 L2 = *reinterpret_cast<const float4*>(capb + 2 * HW);
            float4 L3 = *reinterpret_cast<const float4*>(capb + 3 * HW);
            float4 L4 = *reinterpret_cast<const float4*>(capb + 4 * HW);
            float4 L5 = *reinterpret_cast<const float4*>(capb + 5 * HW);
            float4 L6 = *reinterpret_cast<const float4*>(capb + 6 * HW);
            float4 L7 = *reinterpret_cast<const float4*>(capb + 7 * HW);
            #define STPX(i, COMP) do { \
                uint4 w_; \
                w_.x = (unsigned)f2bf(L0.COMP) | ((unsigned)f2bf(L1.COMP) << 16); \
                w_.y = (unsigned)f2bf(L2.COMP) | ((unsigned)f2bf(L3.COMP) << 16); \
                w_.z = (unsigned)f2bf(L4.COMP) | ((unsigned)f2bf(L5.COMP) << 16); \
                w_.w = (unsigned)f2bf(L6.COMP) | ((unsigned)f2bf(L7.COMP) << 16); \
                *reinterpret_cast<uint4*>(&xs[((u + 1) * 34 + (v0 + (i) + 1)) * 24 + dgrp * 8]) = w_; \
            } while (0)
            STPX(0, x); STPX(1, y); STPX(2, z); STPX(3, w);
            #undef STPX
        }
    }
    __syncthreads();

    const int l = tid & 63;
    const int wv = tid >> 6;          // 0..3
    const int lg = l >> 5;
    const int v = l & 31;
    const bf16x8* wf = reinterpret_cast<const bf16x8*>(wfrag);
    constexpr int OFFS[9] = {0, 48, 96, 1632, 1680, 1728, 3264, 3312, 3360};

    #define EPILOG(C, DD) do { \
        const size_t idx_ = ((size_t)(b * 8 + o) * 16 + (DD)) * 1024 + px; \
        float s10 = (C[0] + C[4]) + (C[8] + C[12]); \
        float s11 = (C[1] + C[5]) + (C[9] + C[13]); \
        float s12 = (C[2] + C[6]) + (C[10] + C[14]); \
        float s13 = (C[3] + C[7]) + (C[11] + C[15]); \
        float vsum = (s10 + s11) + (s12 + s13); \
        float vmax = fmaxf( \
            fmaxf(fmaxf(fmaxf(C[0], C[1]), fmaxf(C[2], C[3])), \
                  fmaxf(fmaxf(C[4], C[5]), fmaxf(C[6], C[7]))), \
            fmaxf(fmaxf(fmaxf(C[8], C[9]), fmaxf(C[10], C[11])), \
                  fmaxf(fmaxf(C[12], C[13]), fmaxf(C[14], C[15])))); \
        float s20 = fmaf(C[0], C[0], fmaf(C[4], C[4], fmaf(C[8], C[8], C[12] * C[12]))); \
        float s21 = fmaf(C[1], C[1], fmaf(C[5], C[5], fmaf(C[9], C[9], C[13] * C[13]))); \
        float s22 = fmaf(C[2], C[2], fmaf(C[6], C[6], fmaf(C[10], C[10], C[14] * C[14]))); \
        float s23 = fmaf(C[3], C[3], fmaf(C[7], C[7], fmaf(C[11], C[11], C[15] * C[15]))); \
        float wsp = 0.f, amp = 0.f; \
        { float mean = 0.25f * s10; float var = fmaxf(fmaf(-mean, mean, 0.25f * s20), 1e-30f); \
          float rq = rsqrtf(var); wsp += rq; amp = fmaf(rq, mean, amp); } \
        { float mean = 0.25f * s11; float var = fmaxf(fmaf(-mean, mean, 0.25f * s21), 1e-30f); \
          float rq = rsqrtf(var); wsp += rq; amp = fmaf(rq, mean, amp); } \
        { float mean = 0.25f * s12; float var = fmaxf(fmaf(-mean, mean, 0.25f * s22), 1e-30f); \
          float rq = rsqrtf(var); wsp += rq; amp = fmaf(rq, mean, amp); } \
        { float mean = 0.25f * s13; float var = fmaxf(fmaf(-mean, mean, 0.25f * s23), 1e-30f); \
          float rq = rsqrtf(var); wsp += rq; amp = fmaf(rq, mean, amp); } \
        vmax = fmaxf(vmax, __shfl_xor(vmax, 32)); \
        vsum += __shfl_xor(vsum, 32); \
        wsp += __shfl_xor(wsp, 32); \
        amp += __shfl_xor(amp, 32); \
        if (l < 32) { pmax[idx_] = vmax; accm_g[idx_] = amp; } \
        else { pmean[idx_] = vsum * (1.f / 32.f); wsum_g[idx_] = wsp; } \
    } while (0)

    for (int dp = 0; dp < 4; ++dp) {
        const int d0 = dh * 8 + dp * 2, d1 = d0 + 1;
        bf16x8 af0[9], af1[9];
        #pragma unroll
        for (int kk = 0; kk < 9; ++kk) {
            af0[kk] = wf[(size_t)((o * 16 + d0) * 10 + kk) * 64 + l];
            af1[kk] = wf[(size_t)((o * 16 + d1) * 10 + kk) * 64 + l];
        }
        const float* bp0 = biasperm + ((o * 16 + d0) * 2 + lg) * 16;
        const float* bp1 = biasperm + ((o * 16 + d1) * 2 + lg) * 16;
        f32x16 ci0, ci1;
        #pragma unroll
        for (int r = 0; r < 16; ++r) { ci0[r] = bp0[r]; ci1[r] = bp1[r]; }

        for (int nt = 0; nt < 8; ++nt) {
            const int u = wv * 8 + nt;
            const int baddr = (u * 34 + v) * 48 + lg * 16;
            f32x16 c0 = ci0, c1 = ci1;
            #pragma unroll
            for (int kk = 0; kk < 9; ++kk) {
                bf16x8 bb = *reinterpret_cast<const bf16x8*>(
                    reinterpret_cast<const char*>(xs) + baddr + OFFS[kk]);
                c0 = __builtin_amdgcn_mfma_f32_32x32x16_bf16(af0[kk], bb, c0, 0, 0, 0);
                c1 = __builtin_amdgcn_mfma_f32_32x32x16_bf16(af1[kk], bb, c1, 0, 0, 0);
            }
            const int px = u * 32 + v;
            EPILOG(c0, d0);
            EPILOG(c1, d1);
        }
    }
    #undef EPILOG
}

// ===== Kernel 2: d-marching 3x3x3 stencil + BN partials (proven r10) ========
__global__ __launch_bounds__(256) void stencil_kernel(
        const float* __restrict__ pmax, const float* __restrict__ pmean,
        const float* __restrict__ Wsp, float* __restrict__ g, float* __restrict__ stats)
{
    __shared__ float sm[2][2][34 * 40];   // 21,760 B
    __shared__ float red[8];
    const int tid = threadIdx.x;
    const int kslab = blockIdx.x & 1;
    const int o = (blockIdx.x >> 1) & 7;
    const int b = blockIdx.x >> 4;
    const int u = tid >> 3;
    const int v4 = (tid & 7) * 4;
    const size_t base = ((size_t)(b * CO + o) * DOUT) * HW;
    const int prow = u * SS + v4;
    const int d0 = kslab * 8;

    for (int i = tid; i < 2 * 2 * 34 * 40; i += 256) (&sm[0][0][0])[i] = 0.f;
    float4 ix, in_;
    const bool first_valid = (d0 - 1 >= 0);
    if (first_valid) {
        ix = *reinterpret_cast<const float4*>(pmax + base + (size_t)(d0 - 1) * HW + prow);
        in_ = *reinterpret_cast<const float4*>(pmean + base + (size_t)(d0 - 1) * HW + prow);
    }
    __syncthreads();
    if (first_valid) {
        *reinterpret_cast<float4*>(&sm[0][0][(u + 1) * 40 + v4 + 4]) = ix;
        *reinterpret_cast<float4*>(&sm[0][1][(u + 1) * 40 + v4 + 4]) = in_;
    }
    __syncthreads();

    float4 A0 = make_float4(0.f, 0.f, 0.f, 0.f);
    float4 A1 = make_float4(0.f, 0.f, 0.f, 0.f);
    float bnsum = 0.f, bnsq = 0.f;

    for (int i = 0; i < 10; ++i) {
        const int p = d0 - 1 + i;
        const int slot = i & 1;
        const bool vnext = (i < 9) && (d0 + i <= 15);
        float4 nx, nn;
        if (vnext) {
            nx = *reinterpret_cast<const float4*>(pmax + base + (size_t)(d0 + i) * HW + prow);
            nn = *reinterpret_cast<const float4*>(pmean + base + (size_t)(d0 + i) * HW + prow);
        }
        float4 A2 = make_float4(0.f, 0.f, 0.f, 0.f);
        if (p >= 0 && p <= 15) {
            #pragma unroll
            for (int a = 0; a < 2; ++a) {
                const float* sp = sm[slot][a];
                #pragma unroll
                for (int du = 0; du < 3; ++du) {
                    const int rb = (u + du) * 40;
                    const float w0 = sp[rb + v4 + 3];
                    const float4 m4 = *reinterpret_cast<const float4*>(&sp[rb + v4 + 4]);
                    const float w5 = sp[rb + v4 + 8];
                    const float w1 = m4.x, w2 = m4.y, w3 = m4.z, w4 = m4.w;
                    const int wb = a * 27 + du * 3;
                    {
                        const float c0 = Wsp[wb + 18], c1 = Wsp[wb + 19], c2 = Wsp[wb + 20];
                        A0.x += c0 * w0 + c1 * w1 + c2 * w2;
                        A0.y += c0 * w1 + c1 * w2 + c2 * w3;
                        A0.z += c0 * w2 + c1 * w3 + c2 * w4;
                        A0.w += c0 * w3 + c1 * w4 + c2 * w5;
                    }
                    {
                        const float c0 = Wsp[wb + 9], c1 = Wsp[wb + 10], c2 = Wsp[wb + 11];
                        A1.x += c0 * w0 + c1 * w1 + c2 * w2;
                        A1.y += c0 * w1 + c1 * w2 + c2 * w3;
                        A1.z += c0 * w2 + c1 * w3 + c2 * w4;
                        A1.w += c0 * w3 + c1 * w4 + c2 * w5;
                    }
                    {
                        const float c0 = Wsp[wb + 0], c1 = Wsp[wb + 1], c2 = Wsp[wb + 2];
                        A2.x += c0 * w0 + c1 * w1 + c2 * w2;
                        A2.y += c0 * w1 + c1 * w2 + c2 * w3;
                        A2.z += c0 * w2 + c1 * w3 + c2 * w4;
                        A2.w += c0 * w3 + c1 * w4 + c2 * w5;
                    }
                }
            }
        }
        if (p - 1 >= d0 && p - 1 < d0 + 8) {
            *reinterpret_cast<float4*>(&g[base + (size_t)(p - 1) * HW + prow]) = A0;
            bnsum += A0.x + A0.y + A0.z + A0.w;
            bnsq += A0.x * A0.x + A0.y * A0.y + A0.z * A0.z + A0.w * A0.w;
        }
        A0 = A1; A1 = A2;
        if (vnext) {
            *reinterpret_cast<float4*>(&sm[slot ^ 1][0][(u + 1) * 40 + v4 + 4]) = nx;
            *reinterpret_cast<float4*>(&sm[slot ^ 1][1][(u + 1) * 40 + v4 + 4]) = nn;
        }
        __syncthreads();
    }

    #pragma unroll
    for (int off = 32; off > 0; off >>= 1) {
        bnsum += __shfl_down(bnsum, off);
        bnsq += __shfl_down(bnsq, off);
    }
    if ((tid & 63) == 0) { red[tid >> 6] = bnsum; red[4 + (tid >> 6)] = bnsq; }
    __syncthreads();
    if (tid == 0) {
        atomicAdd(&stats[ST_BNSUM + o], red[0] + red[1] + red[2] + red[3]);
        atomicAdd(&stats[ST_BNSQ + o], red[4] + red[5] + red[6] + red[7]);
    }
}

// ===== Kernel 3: BN -> sigmoid gate -> caps_next + LN partials (proven) =====
__global__ __launch_bounds__(256) void finalize_kernel(
        const float* __restrict__ g, const float* __restrict__ accm_g,
        const float* __restrict__ wsum_g,
        const float* __restrict__ bn_gamma, const float* __restrict__ bn_beta,
        float* __restrict__ cn, float* __restrict__ stats)
{
    const int d = blockIdx.x & 15;
    const int o = (blockIdx.x >> 4) & 7;
    const int b = blockIdx.x >> 7;
    const int px0 = threadIdx.x * 4;

    const float nbn = 1.f / (float)(BATCH * DOUT * HW);
    const float mu = stats[ST_BNSUM + o] * nbn;
    const float var = fmaxf(stats[ST_BNSQ + o] * nbn - mu * mu, 0.f);
    const float rstd = rsqrtf(var + EPSF);
    const float gam = bn_gamma[0], bet = bn_beta[0];

    const size_t gbase = (((size_t)b * CO + o) * DOUT + d) * HW + px0;
    float4 g4 = *reinterpret_cast<const float4*>(&g[gbase]);
    float4 a4 = *reinterpret_cast<const float4*>(&accm_g[gbase]);
    float4 w4 = *reinterpret_cast<const float4*>(&wsum_g[gbase]);
    float4 cnv;
    cnv.x = (1.f + 1.f / (1.f + expf(-((g4.x - mu) * rstd * gam + bet)))) * a4.x / w4.x;
    cnv.y = (1.f + 1.f / (1.f + expf(-((g4.y - mu) * rstd * gam + bet)))) * a4.y / w4.y;
    cnv.z = (1.f + 1.f / (1.f + expf(-((g4.z - mu) * rstd * gam + bet)))) * a4.z / w4.z;
    cnv.w = (1.f + 1.f / (1.f + expf(-((g4.w - mu) * rstd * gam + bet)))) * a4.w / w4.w;
    *reinterpret_cast<float4*>(&cn[gbase]) = cnv;

    float s = cnv.x + cnv.y + cnv.z + cnv.w;
    float sq = cnv.x * cnv.x + cnv.y * cnv.y + cnv.z * cnv.z + cnv.w * cnv.w;
    wave_reduce_atomic2(s, sq, &stats[ST_LNSUM + b * CO + o], &stats[ST_LNSQ + b * CO + o]);
}

// ===== Kernel 4: LayerNorm + transpose-out (proven) =========================
__global__ __launch_bounds__(256) void ln_kernel(
        const float* __restrict__ cn, const float* __restrict__ stats,
        const float* __restrict__ lng, const float* __restrict__ lnb,
        float* __restrict__ out)
{
    const int bo = blockIdx.x;
    const int b = bo >> 3, o = bo & 7;
    const float nln = 1.f / 16384.f;
    const float mu = stats[ST_LNSUM + bo] * nln;
    const float var = fmaxf(stats[ST_LNSQ + bo] * nln - mu * mu, 0.f);
    const float rstd = rsqrtf(var + EPSF);
    const float* src = cn + (size_t)bo * 16384;
    float* dst = out + ((size_t)o * BATCH + b) * 16384;
    #pragma unroll
    for (int i = 0; i < 16; i++) {
        const int e = i * 1024 + threadIdx.x * 4;
        float4 x = *reinterpret_cast<const float4*>(src + e);
        float4 gm = *reinterpret_cast<const float4*>(lng + e);
        float4 bb = *reinterpret_cast<const float4*>(lnb + e);
        float4 y;
        y.x = (x.x - mu) * rstd * gm.x + bb.x;
        y.y = (x.y - mu) * rstd * gm.y + bb.y;
        y.z = (x.z - mu) * rstd * gm.z + bb.z;
        y.w = (x.w - mu) * rstd * gm.w + bb.w;
        *reinterpret_cast<float4*>(dst + e) = y;
    }
}

extern "C" void kernel_launch(void* const* d_in, const int* in_sizes, int n_in,
                              void* d_out, int out_size, void* d_ws, size_t ws_size,
                              hipStream_t stream) {
    const float* caps = (const float*)d_in[0];
    const float* Wt   = (const float*)d_in[1];
    const float* bt   = (const float*)d_in[2];
    const float* Wv   = (const float*)d_in[3];
    const float* bv   = (const float*)d_in[4];
    const float* Wsp  = (const float*)d_in[5];
    const float* bng  = (const float*)d_in[6];
    const float* bnb  = (const float*)d_in[7];
    const float* lng  = (const float*)d_in[8];
    const float* lnb  = (const float*)d_in[9];
    float* ws = (float*)d_ws;
    float* pmax  = ws + OFF_PMAX;
    float* pmean = ws + OFF_PMEAN;
    float* accm  = ws + OFF_ACCM;
    float* wsum  = ws + OFF_WSUM;
    float* g     = ws + OFF_G;
    float* cn    = ws + OFF_CN;
    float* stats = ws + OFF_STATS;
    ushort* wfrag = (ushort*)(ws + OFF_WFRAG);
    float* biasperm = ws + OFF_BIASP;
    float* out = (float*)d_out;

    hipMemsetAsync(stats, 0, STATS_FLOATS * sizeof(float), stream);
    wfrag_kernel<<<336, 256, 0, stream>>>(Wt, bt, Wv, bv, wfrag, biasperm);
    convmfma_kernel<<<dim3(16, 32), 256, 0, stream>>>(caps, wfrag, biasperm,
                                                      pmax, pmean, accm, wsum);
    stencil_kernel<<<512, 256, 0, stream>>>(pmax, pmean, Wsp, g, stats);
    finalize_kernel<<<4096, 256, 0, stream>>>(g, accm, wsum, bng, bnb, cn, stats);
    ln_kernel<<<256, 256, 0, stream>>>(cn, stats, lng, lnb, out);
}